// Round 5
// baseline (272.067 us; speedup 1.0000x reference)
//
#include <hip/hip_runtime.h>

// YOLO loss: preds/targets (N,7,7,30) fp32 -> scalar. 192.7 MB read.
// R5: (a) spill-free register-dbuf pipeline (__launch_bounds__(64,1) --
// R3's version spilled 120 prefetch floats to scratch: WRITE_SIZE 174 MB);
// (b) probe_full: full-size 192.7 MB pure coalesced read-reduce to test the
// "~2.55 TB/s L3-resident read ceiling" theory (R0-R2 all consumed at
// exactly 2.55 TB/s regardless of structure, incl. a pure-L3 replay).

#define SGRID 7
#define DDIM 30
#define NCLS 20
#define LAMBDA_NOOBJ 0.5f
#define IOU_EPS 1e-10f

#define SLICE_CELLS 64
#define SLICE_FLOATS (SLICE_CELLS * DDIM)  // 1920 floats = 7.68 KB
#define MAIN_BLOCKS 2560                   // one 64-lane wave per block

#define PROBE_BLOCKS 2048
#define PROBE_THREADS 256

// pv/tv point into LDS (per-cell, constant offsets -> ds_read).
__device__ __forceinline__ float cell_loss(const float* pv, const float* tv) {
    float loss = 0.0f;
    float iou0 = 0.0f, iou1 = 0.0f;
#pragma unroll
    for (int b = 0; b < 2; ++b) {
        const float x1 = pv[b * 5 + 0], y1 = pv[b * 5 + 1];
        const float w1 = pv[b * 5 + 2], h1 = pv[b * 5 + 3];
        const float x2 = tv[b * 5 + 0], y2 = tv[b * 5 + 1];
        const float w2 = tv[b * 5 + 2], h2 = tv[b * 5 + 3];
        float iw = fminf(x1 + 0.5f * w1, x2 + 0.5f * w2) -
                   fmaxf(x1 - 0.5f * w1, x2 - 0.5f * w2);
        iw = fmaxf(iw, 0.0f);
        float ih = fminf(y1 + 0.5f * h1, y2 + 0.5f * h2) -
                   fmaxf(y1 - 0.5f * h1, y2 - 0.5f * h2);
        ih = fmaxf(ih, 0.0f);
        const float inter = iw * ih;
        const float uni = w1 * h1 + w2 * h2 - inter;
        const float iou = inter / (uni + IOU_EPS);
        if (b == 0) iou0 = iou; else iou1 = iou;
    }
    const bool sel1 = iou1 > iou0;  // argmax ties -> box 0

    {   // coord loss, gated by has_obj = targets[...,4] > 0
        const float px = sel1 ? pv[5] : pv[0];
        const float py = sel1 ? pv[6] : pv[1];
        const float tx = sel1 ? tv[5] : tv[0];
        const float ty = sel1 ? tv[6] : tv[1];
        const float dx = px - tx, dy = py - ty;
        if (tv[4] > 0.0f) loss += dx * dx + dy * dy;
    }

    // class SSE + running argmax of target class (ties -> first),
    // tracking pred-at-gt-class by value.
    float gt_val = tv[10];
    float pc_gt = pv[10];
#pragma unroll
    for (int j = 0; j < NCLS; ++j) {
        const float pc = pv[10 + j], tc = tv[10 + j];
        const float d = pc - tc;
        loss += d * d;
        const bool gm = tc > gt_val;
        gt_val = gm ? tc : gt_val;
        pc_gt = gm ? pc : pc_gt;
    }

    // conf loss: w_b * iou_b^2 * (pc_gt - 1)^2
    const float c = pc_gt - 1.0f;
    const float d0 = iou0 * c, d1 = iou1 * c;
    const float w0 = sel1 ? LAMBDA_NOOBJ : 1.0f;
    const float w1 = sel1 ? 1.0f : LAMBDA_NOOBJ;
    loss += w0 * d0 * d0 + w1 * d1 * d1;
    return loss;
}

__device__ __forceinline__ void load_slice(const float* __restrict__ g, int lane,
                                           float4 (&r)[7], float2& r2) {
    const float4* g4 = (const float4*)g;
#pragma unroll
    for (int k = 0; k < 7; ++k) r[k] = g4[lane + (k << 6)];
    r2 = ((const float2*)g)[896 + lane];
}

__device__ __forceinline__ void store_slice(float* l, int lane,
                                            const float4 (&r)[7], const float2& r2) {
#pragma unroll
    for (int k = 0; k < 7; ++k) ((float4*)l)[lane + (k << 6)] = r[k];
    ((float2*)l)[896 + lane] = r2;
}

// __launch_bounds__(64, 1): min 1 wave/EU -> VGPR budget up to 512, so the
// 2x60-float prefetch buffers live in registers (R3's default bound spilled
// them to scratch: 174 MB of junk writes). LDS 15.4 KB -> 10 blocks/CU.
__global__ __launch_bounds__(64, 1) void yolo_loss_main(
    const float* __restrict__ preds, const float* __restrict__ targets,
    float* __restrict__ partials, int n_cells) {
    __shared__ float lp[SLICE_FLOATS];  // one wave per block: wave-private
    __shared__ float lt[SLICE_FLOATS];

    const int lane = threadIdx.x;
    const int nwaves = gridDim.x;
    const int n_slices = n_cells / SLICE_CELLS;

    float loss = 0.0f;
    int s = blockIdx.x;

    float4 ap[7], at[7]; float2 ap2, at2;
    float4 bp[7], bt[7]; float2 bp2, bt2;

    if (s < n_slices) {
        load_slice(preds + (size_t)s * SLICE_FLOATS, lane, ap, ap2);
        load_slice(targets + (size_t)s * SLICE_FLOATS, lane, at, at2);
    }
    while (s < n_slices) {
        // phase A: commit A-regs to LDS, prefetch next slice into B-regs
        // (its vmcnt overlaps the LDS-read + compute below), consume.
        store_slice(lp, lane, ap, ap2);
        store_slice(lt, lane, at, at2);
        {
            const int s2 = s + nwaves;
            if (s2 < n_slices) {
                load_slice(preds + (size_t)s2 * SLICE_FLOATS, lane, bp, bp2);
                load_slice(targets + (size_t)s2 * SLICE_FLOATS, lane, bt, bt2);
            }
            loss += cell_loss(lp + lane * DDIM, lt + lane * DDIM);
            s = s2;
        }
        if (s >= n_slices) break;
        // phase B: mirror. DS ops are wave-in-order; wave-private slice ->
        // no barrier needed.
        store_slice(lp, lane, bp, bp2);
        store_slice(lt, lane, bt, bt2);
        {
            const int s2 = s + nwaves;
            if (s2 < n_slices) {
                load_slice(preds + (size_t)s2 * SLICE_FLOATS, lane, ap, ap2);
                load_slice(targets + (size_t)s2 * SLICE_FLOATS, lane, at, at2);
            }
            loss += cell_loss(lp + lane * DDIM, lt + lane * DDIM);
            s = s2;
        }
    }

    // Tail cells (dead for this shape: 802816 = 64*12544).
    const int tail0 = n_slices * SLICE_CELLS;
    if (blockIdx.x == 0 && tail0 + lane < n_cells) {
        float pv[DDIM], tv[DDIM];
        const float* gp = preds + (size_t)(tail0 + lane) * DDIM;
        const float* gt = targets + (size_t)(tail0 + lane) * DDIM;
#pragma unroll
        for (int i = 0; i < DDIM; ++i) { pv[i] = gp[i]; tv[i] = gt[i]; }
        loss += cell_loss(pv, tv);
    }

#pragma unroll
    for (int off = 32; off > 0; off >>= 1) loss += __shfl_down(loss, off, 64);
    if (lane == 0) partials[blockIdx.x] = loss;
}

#define RTHREADS 1024
__global__ __launch_bounds__(RTHREADS) void yolo_loss_reduce(
    const float* __restrict__ partials, int n, float inv_n,
    float* __restrict__ out) {
    __shared__ float red[RTHREADS / 64];
    float v = 0.0f;
    for (int i = threadIdx.x; i < n; i += RTHREADS) v += partials[i];
#pragma unroll
    for (int off = 32; off > 0; off >>= 1) v += __shfl_down(v, off, 64);
    if ((threadIdx.x & 63) == 0) red[threadIdx.x >> 6] = v;
    __syncthreads();
    if (threadIdx.x == 0) {
        float s = 0.0f;
#pragma unroll
        for (int w = 0; w < RTHREADS / 64; ++w) s += red[w];
        out[0] = s * inv_n;
    }
}

// Diagnostic: FULL-SIZE pure coalesced read of both tensors (192.7 MB),
// no LDS, no per-cell compute. If this also runs at ~2.55 TB/s (~75 us),
// the ceiling is the data path (L3-resident read rate), not my structure.
__global__ __launch_bounds__(PROBE_THREADS) void probe_full(
    const float4* __restrict__ a, const float4* __restrict__ b, int nf4,
    float* __restrict__ sink) {
    const int stride = PROBE_BLOCKS * PROBE_THREADS;
    float v = 0.0f;
    for (int i = blockIdx.x * PROBE_THREADS + threadIdx.x; i < nf4; i += stride) {
        const float4 x = a[i];
        v += x.x + x.y + x.z + x.w;
    }
    for (int i = blockIdx.x * PROBE_THREADS + threadIdx.x; i < nf4; i += stride) {
        const float4 x = b[i];
        v += x.x + x.y + x.z + x.w;
    }
#pragma unroll
    for (int off = 32; off > 0; off >>= 1) v += __shfl_down(v, off, 64);
    __shared__ float red[PROBE_THREADS / 64];
    if ((threadIdx.x & 63) == 0) red[threadIdx.x >> 6] = v;
    __syncthreads();
    if (threadIdx.x == 0) {
        float s = 0.0f;
#pragma unroll
        for (int w = 0; w < PROBE_THREADS / 64; ++w) s += red[w];
        sink[blockIdx.x] = s;
    }
}

extern "C" void kernel_launch(void* const* d_in, const int* in_sizes, int n_in,
                              void* d_out, int out_size, void* d_ws, size_t ws_size,
                              hipStream_t stream) {
    const float* preds = (const float*)d_in[0];
    const float* targets = (const float*)d_in[1];
    float* out = (float*)d_out;

    const int total = in_sizes[0];                 // N*S*S*D
    const int n_cells = total / DDIM;              // N*S*S
    const int N = total / (SGRID * SGRID * DDIM);  // 16384

    float* partials = (float*)d_ws;                 // [0, MAIN_BLOCKS)
    float* probe_sink = (float*)d_ws + MAIN_BLOCKS; // [MAIN_BLOCKS, +PROBE_BLOCKS)

    yolo_loss_main<<<MAIN_BLOCKS, 64, 0, stream>>>(preds, targets, partials,
                                                   n_cells);
    yolo_loss_reduce<<<1, RTHREADS, 0, stream>>>(partials, MAIN_BLOCKS,
                                                 1.0f / (float)N, out);
    probe_full<<<PROBE_BLOCKS, PROBE_THREADS, 0, stream>>>(
        (const float4*)preds, (const float4*)targets, total / 4, probe_sink);
}

// Round 6
// 208.708 us; speedup vs baseline: 1.3036x; 1.3036x over previous
//
#include <hip/hip_runtime.h>

// YOLO loss: preds/targets (N,7,7,30) fp32 -> scalar. 192.7 MB read.
// R6: occupancy fix. R5's probe proved the data path does ~6+ TB/s; the
// main kernel was latency-bound at 10 waves/CU (LDS-capped, marginal
// stall coverage). Slice = 32 cells -> 7.68 KB/wave -> 20 waves/CU, with
// tiny register footprint (~60 VGPR) so the allocator's 64-VGPR/8-wave
// heuristic doesn't spill (R3/R5: 120-float prefetch arrays -> 174 MB of
// scratch writes at VGPR_Count 68). No barriers; wave-private LDS slice;
// DS-FIFO ordering makes the single buffer safe across iterations.

#define SGRID 7
#define DDIM 30
#define NCLS 20
#define LAMBDA_NOOBJ 0.5f
#define IOU_EPS 1e-10f

#define SLICE_CELLS 32
#define SLICE_FLOATS (SLICE_CELLS * DDIM)  // 960 floats = 3.84 KB
#define SLICE_F4 (SLICE_FLOATS / 4)        // 240
#define THREADS 128                        // 2 waves/block
#define WPB (THREADS / 64)
#define GRID_BLOCKS 2560                   // 10 blocks/CU * 256 CU

// pv/tv point into LDS (constant per-cell offsets -> ds_read).
__device__ __forceinline__ float cell_loss(const float* pv, const float* tv) {
    float loss = 0.0f;
    float iou0 = 0.0f, iou1 = 0.0f;
#pragma unroll
    for (int b = 0; b < 2; ++b) {
        const float x1 = pv[b * 5 + 0], y1 = pv[b * 5 + 1];
        const float w1 = pv[b * 5 + 2], h1 = pv[b * 5 + 3];
        const float x2 = tv[b * 5 + 0], y2 = tv[b * 5 + 1];
        const float w2 = tv[b * 5 + 2], h2 = tv[b * 5 + 3];
        float iw = fminf(x1 + 0.5f * w1, x2 + 0.5f * w2) -
                   fmaxf(x1 - 0.5f * w1, x2 - 0.5f * w2);
        iw = fmaxf(iw, 0.0f);
        float ih = fminf(y1 + 0.5f * h1, y2 + 0.5f * h2) -
                   fmaxf(y1 - 0.5f * h1, y2 - 0.5f * h2);
        ih = fmaxf(ih, 0.0f);
        const float inter = iw * ih;
        const float uni = w1 * h1 + w2 * h2 - inter;
        const float iou = inter / (uni + IOU_EPS);
        if (b == 0) iou0 = iou; else iou1 = iou;
    }
    const bool sel1 = iou1 > iou0;  // argmax ties -> box 0

    {   // coord loss, gated by has_obj = targets[...,4] > 0
        const float px = sel1 ? pv[5] : pv[0];
        const float py = sel1 ? pv[6] : pv[1];
        const float tx = sel1 ? tv[5] : tv[0];
        const float ty = sel1 ? tv[6] : tv[1];
        const float dx = px - tx, dy = py - ty;
        if (tv[4] > 0.0f) loss += dx * dx + dy * dy;
    }

    // class SSE + running argmax of target class (ties -> first),
    // tracking pred-at-gt-class by value (no dynamic indexing).
    float gt_val = tv[10];
    float pc_gt = pv[10];
#pragma unroll
    for (int j = 0; j < NCLS; ++j) {
        const float pc = pv[10 + j], tc = tv[10 + j];
        const float d = pc - tc;
        loss += d * d;
        const bool gm = tc > gt_val;
        gt_val = gm ? tc : gt_val;
        pc_gt = gm ? pc : pc_gt;
    }

    // conf loss: w_b * iou_b^2 * (pc_gt - 1)^2
    const float c = pc_gt - 1.0f;
    const float d0 = iou0 * c, d1 = iou1 * c;
    const float w0 = sel1 ? LAMBDA_NOOBJ : 1.0f;
    const float w1 = sel1 ? 1.0f : LAMBDA_NOOBJ;
    loss += w0 * d0 * d0 + w1 * d1 * d1;
    return loss;
}

__global__ __launch_bounds__(THREADS) void yolo_loss_main(
    const float* __restrict__ preds, const float* __restrict__ targets,
    float* __restrict__ partials, int n_cells) {
    // Wave-private slices: 2 waves/block * (3.84 + 3.84) KB = 15.36 KB/block
    // -> 10 blocks/CU -> 20 waves/CU (2x R2's occupancy).
    __shared__ float lp[WPB][SLICE_FLOATS];
    __shared__ float lt[WPB][SLICE_FLOATS];
    __shared__ float red[WPB];

    const int tid = threadIdx.x;
    const int lane = tid & 63;
    const int wlocal = tid >> 6;
    const int gw = blockIdx.x * WPB + wlocal;
    const int nw = GRID_BLOCKS * WPB;       // 5120 waves
    const int n_slices = n_cells / SLICE_CELLS;  // 25088 (exact)

    float* Lp = lp[wlocal];
    float* Lt = lt[wlocal];

    float loss = 0.0f;
    for (int s = gw; s < n_slices; s += nw) {
        const float4* gp = (const float4*)(preds + (size_t)s * SLICE_FLOATS);
        const float4* gt = (const float4*)(targets + (size_t)s * SLICE_FLOATS);
        // Stage 32 cells: 240 float4 per tensor over 64 lanes (3 full
        // rounds + 48-lane round). <=16 floats live per lane -> no spill.
#pragma unroll
        for (int k = 0; k < 4; ++k) {
            const int i = lane + (k << 6);
            if (i < SLICE_F4) {
                const float4 a = gp[i];
                const float4 b = gt[i];
                ((float4*)Lp)[i] = a;
                ((float4*)Lt)[i] = b;
            }
        }
        // Wave-private slice: compiler's vmcnt/lgkmcnt deps suffice, no
        // barrier. DS ops are wave-FIFO, so next iteration's writes cannot
        // pass this iteration's reads.
        if (lane < SLICE_CELLS)
            loss += cell_loss(Lp + lane * DDIM, Lt + lane * DDIM);
    }

    // Tail cells (dead for this shape: 802816 = 32*25088).
    const int tail0 = n_slices * SLICE_CELLS;
    if (blockIdx.x == 0 && wlocal == 0 && tail0 + lane < n_cells) {
        float pv[DDIM], tv[DDIM];
        const float* gp = preds + (size_t)(tail0 + lane) * DDIM;
        const float* gt = targets + (size_t)(tail0 + lane) * DDIM;
#pragma unroll
        for (int i = 0; i < DDIM; ++i) { pv[i] = gp[i]; tv[i] = gt[i]; }
        loss += cell_loss(pv, tv);
    }

    // Block reduction (one barrier, outside the hot loop).
#pragma unroll
    for (int off = 32; off > 0; off >>= 1) loss += __shfl_down(loss, off, 64);
    if (lane == 0) red[wlocal] = loss;
    __syncthreads();
    if (tid == 0) {
        float s = 0.0f;
#pragma unroll
        for (int w = 0; w < WPB; ++w) s += red[w];
        partials[blockIdx.x] = s;
    }
}

#define RTHREADS 1024
__global__ __launch_bounds__(RTHREADS) void yolo_loss_reduce(
    const float* __restrict__ partials, int n, float inv_n,
    float* __restrict__ out) {
    __shared__ float red[RTHREADS / 64];
    float v = 0.0f;
    for (int i = threadIdx.x; i < n; i += RTHREADS) v += partials[i];
#pragma unroll
    for (int off = 32; off > 0; off >>= 1) v += __shfl_down(v, off, 64);
    if ((threadIdx.x & 63) == 0) red[threadIdx.x >> 6] = v;
    __syncthreads();
    if (threadIdx.x == 0) {
        float s = 0.0f;
#pragma unroll
        for (int w = 0; w < RTHREADS / 64; ++w) s += red[w];
        out[0] = s * inv_n;
    }
}

extern "C" void kernel_launch(void* const* d_in, const int* in_sizes, int n_in,
                              void* d_out, int out_size, void* d_ws, size_t ws_size,
                              hipStream_t stream) {
    const float* preds = (const float*)d_in[0];
    const float* targets = (const float*)d_in[1];
    float* out = (float*)d_out;

    const int total = in_sizes[0];                 // N*S*S*D
    const int n_cells = total / DDIM;              // N*S*S
    const int N = total / (SGRID * SGRID * DDIM);  // 16384

    float* partials = (float*)d_ws;  // GRID_BLOCKS floats, fully written

    yolo_loss_main<<<GRID_BLOCKS, THREADS, 0, stream>>>(preds, targets,
                                                        partials, n_cells);
    yolo_loss_reduce<<<1, RTHREADS, 0, stream>>>(partials, GRID_BLOCKS,
                                                 1.0f / (float)N, out);
}